// Round 13
// baseline (6650.999 us; speedup 1.0000x reference)
//
#include <hip/hip_runtime.h>

typedef _Float16 h8 __attribute__((ext_vector_type(8)));
typedef float f32x4 __attribute__((ext_vector_type(4)));

#define NB 128
#define NT 2048
#define NIN 32
#define NS 32
#define NM 8
#define NE 64
#define NH 128
#define NH3 384
#define BPB 16

__device__ __forceinline__ float rcpf(float v) {
#if __has_builtin(__builtin_amdgcn_rcpf)
  return __builtin_amdgcn_rcpf(v);
#else
  return 1.0f / v;
#endif
}
__device__ __forceinline__ float sigmoid_f(float v) { return rcpf(1.0f + __expf(-v)); }
__device__ __forceinline__ float tanh_f(float v) { return 1.0f - 2.0f * rcpf(1.0f + __expf(2.0f * v)); }

#define MFMA(a, b, c) __builtin_amdgcn_mfma_f32_16x16x32_f16((a), (b), (c), 0, 0, 0)

__global__ __launch_bounds__(512, 1) void rnn_mfma2(
    const float* __restrict__ gx, const float* __restrict__ gy,
    const float* __restrict__ W_enc, const float* __restrict__ b_enc,
    const float* __restrict__ W_in, const float* __restrict__ W_rec,
    const float* __restrict__ b_s, const float* __restrict__ W_x,
    const float* __restrict__ W_h, const float* __restrict__ b_x,
    const float* __restrict__ b_h, const float* __restrict__ W_gate,
    const float* __restrict__ b_gate, float* __restrict__ out) {
  const int tid = threadIdx.x;
  const int w = tid >> 6, l = tid & 63;
  const int col = l & 15, kg = l >> 4, rb = kg * 4;
  const int bA = l & 15;  // A-fragment row = batch
  const int bg = blockIdx.x;
  const int jc = 16 * w + col;

  // LDS (A-operand tiles XOR-swizzled)
  __shared__ __align__(16) _Float16 xbuf[2][32][BPB][NIN];  // 64 KB, ^((b&3)<<4)
  __shared__ __align__(16) _Float16 h_shm[2][BPB][NH];      // 8 KB,  ^((b&7)<<4)
  __shared__ __align__(16) _Float16 ns_shm[2][BPB][NM][NS]; // 16 KB, ^((b&7)<<4)
  __shared__ __align__(16) _Float16 enc_shm[2][BPB][NE];    // 4 KB,  ^((b&7)<<4)
  __shared__ __align__(16) float g_sh[NM][BPB];             // [m][b]
  __shared__ __align__(16) float y_sh[BPB][128];

  char* xB = (char*)xbuf;
  char* hB = (char*)h_shm;
  char* nsB = (char*)ns_shm;
  char* eB = (char*)enc_shm;

  // ---- weights as B-fragments (r12-verified conventions) ----
  h8 whB[3][4], wxB[3][2], winB[2], wrecB[2], wencB, wgB[4];
  float bh3[3], bx3[3], wxe3[3], bs2[2], be = 0.f, bgv = 0.f;
#pragma unroll
  for (int g = 0; g < 3; ++g) {
    const int j3 = g * NH + jc;
#pragma unroll
    for (int c = 0; c < 4; ++c)
#pragma unroll
      for (int e = 0; e < 8; ++e)
        whB[g][c][e] = (_Float16)W_h[(size_t)(c * 32 + kg * 8 + e) * NH3 + j3];
#pragma unroll
    for (int c = 0; c < 2; ++c)
#pragma unroll
      for (int e = 0; e < 8; ++e)
        wxB[g][c][e] = (_Float16)W_x[(size_t)(c * 32 + kg * 8 + e) * NH3 + j3];
    bh3[g] = b_h[j3];
    bx3[g] = b_x[j3];
    wxe3[g] = W_x[(size_t)NE * NH3 + j3];
  }
#pragma unroll
  for (int t16 = 0; t16 < 2; ++t16) {
    const int s = t16 * 16 + col;
#pragma unroll
    for (int e = 0; e < 8; ++e) {
      winB[t16][e] = (_Float16)W_in[w * 1024 + (kg * 8 + e) * 32 + s];
      wrecB[t16][e] = (_Float16)W_rec[w * 1024 + (kg * 8 + e) * 32 + s];
    }
    bs2[t16] = b_s[w * 32 + s];
  }
#pragma unroll
  for (int e = 0; e < 8; ++e) wencB[e] = (_Float16)0.f;
  if (w < 4) {
#pragma unroll
    for (int e = 0; e < 8; ++e)
      wencB[e] = (_Float16)W_enc[(kg * 8 + e) * NE + 16 * w + col];
    be = b_enc[16 * w + col];
  }
#pragma unroll
  for (int c = 0; c < 4; ++c)
#pragma unroll
    for (int e = 0; e < 8; ++e) wgB[c][e] = (_Float16)0.f;
  if (w == 4) {
#pragma unroll
    for (int c = 0; c < 4; ++c)
#pragma unroll
      for (int e = 0; e < 8; ++e)
        wgB[c][e] = (col < 8) ? (_Float16)W_gate[(c * 32 + kg * 8 + e) * NM + col]
                              : (_Float16)0.f;
    bgv = (col < 8) ? b_gate[col] : -1e30f;
  }

#define XOFF(T) ((((T) >> 5) & 1) * 32768 + ((T)&31) * 1024 + bA * 64 + ((kg * 16) ^ ((bA & 3) << 4)))
#define HOFF(PB, c) ((PB)*4096 + bA * 256 + (((c)*64 + kg * 16) ^ ((bA & 7) << 4)))
#define EOFF(PB, c) ((PB)*2048 + bA * 128 + (((c)*64 + kg * 16) ^ ((bA & 7) << 4)))
#define NSOFF(PB, m) ((PB)*8192 + bA * 512 + (((m)*64 + kg * 16) ^ ((bA & 7) << 4)))

#define LOAD_X_SLAB(BS, TB)                                                    \
  {                                                                            \
    const int d_ = tid >> 4, bb_ = tid & 15;                                   \
    const float4* s4_ = (const float4*)(gx +                                   \
        ((size_t)(bg * BPB + bb_) * NT + min((TB) + d_, NT - 1)) * NIN);       \
    char* xb_ = xB + (BS)*32768 + d_ * 1024 + bb_ * 64;                        \
    _Pragma("unroll")                                                          \
    for (int c_ = 0; c_ < 4; ++c_) {                                           \
      const float4 va_ = s4_[2 * c_], vb_ = s4_[2 * c_ + 1];                   \
      h8 p_;                                                                   \
      p_[0] = (_Float16)va_.x; p_[1] = (_Float16)va_.y;                        \
      p_[2] = (_Float16)va_.z; p_[3] = (_Float16)va_.w;                        \
      p_[4] = (_Float16)vb_.x; p_[5] = (_Float16)vb_.y;                        \
      p_[6] = (_Float16)vb_.z; p_[7] = (_Float16)vb_.w;                        \
      *(h8*)(xb_ + ((c_ * 16) ^ ((bb_ & 3) << 4))) = p_;                       \
    }                                                                          \
  }

#define LOAD_Y_SLAB(TB)                                                        \
  {                                                                            \
    const int b_ = tid >> 5;                                                   \
    const int i0_ = (tid & 31) * 4;                                            \
    const float* yr = gy + (size_t)(bg * BPB + b_) * NT;                       \
    _Pragma("unroll")                                                          \
    for (int u = 0; u < 4; ++u) {                                              \
      const int idx = (TB)-1 + i0_ + u;                                        \
      y_sh[b_][i0_ + u] = yr[idx < 0 ? 0 : idx];                               \
    }                                                                          \
  }

  // ---- prologue: zero state, load slabs, enc(0)/enc(1), xpre(0)/xd(0) ----
  for (int i = tid; i < BPB * NH; i += 512) h_shm[1][i >> 7][i & 127] = (_Float16)0.f;
  for (int i = tid; i < BPB * NM * NS; i += 512)
    ((_Float16*)ns_shm[1])[i] = (_Float16)0.f;
  LOAD_X_SLAB(0, 0)
  LOAD_Y_SLAB(0)
  __syncthreads();

  if (w < 4) {
#pragma unroll
    for (int tt = 0; tt < 2; ++tt) {
      const h8 xA = *(const h8*)(xB + XOFF(tt));
      f32x4 ea = {be, be, be, be};
      ea = MFMA(xA, wencB, ea);
#pragma unroll
      for (int r = 0; r < 4; ++r) {
        const int brow = rb + r;
        *(_Float16*)(eB + tt * 2048 + brow * 128 +
                     (((16 * w + col) * 2) ^ ((brow & 7) << 4))) = (_Float16)tanh_f(ea[r]);
      }
    }
  }
  __syncthreads();

  f32x4 xpaC0, xpaC1, xpaC2, xdaC0, xdaC1;
  {
    h8 encA0 = *(const h8*)(eB + EOFF(0, 0));
    h8 encA1 = *(const h8*)(eB + EOFF(0, 1));
    f32x4 a0 = {bx3[0], bx3[0], bx3[0], bx3[0]};
    f32x4 a1 = {bx3[1], bx3[1], bx3[1], bx3[1]};
    f32x4 a2 = {bx3[2], bx3[2], bx3[2], bx3[2]};
    a0 = MFMA(encA0, wxB[0][0], a0); a0 = MFMA(encA1, wxB[0][1], a0);
    a1 = MFMA(encA0, wxB[1][0], a1); a1 = MFMA(encA1, wxB[1][1], a1);
    a2 = MFMA(encA0, wxB[2][0], a2); a2 = MFMA(encA1, wxB[2][1], a2);
    xpaC0 = a0; xpaC1 = a1; xpaC2 = a2;
    const h8 xA = *(const h8*)(xB + XOFF(0));
    f32x4 d0 = {bs2[0], bs2[0], bs2[0], bs2[0]};
    f32x4 d1 = {bs2[1], bs2[1], bs2[1], bs2[1]};
    xdaC0 = MFMA(xA, winB[0], d0);
    xdaC1 = MFMA(xA, winB[1], d1);
  }
  __syncthreads();

  float h_prev[4] = {0.f, 0.f, 0.f, 0.f};

  for (int t = 0; t < NT; ++t) {
    const int q = t & 1, qp = q ^ 1;
    // ============ Phase A: z/r/n | gate+softmax | enc(t+2) ============
    h8 hA[4];
#pragma unroll
    for (int c = 0; c < 4; ++c) hA[c] = *(const h8*)(hB + HOFF(qp, c));
    f32x4 za = {bh3[0], bh3[0], bh3[0], bh3[0]};
    f32x4 ra = {bh3[1], bh3[1], bh3[1], bh3[1]};
    f32x4 na = {bh3[2], bh3[2], bh3[2], bh3[2]};
#pragma unroll
    for (int c = 0; c < 4; ++c) {
      za = MFMA(hA[c], whB[0][c], za);
      ra = MFMA(hA[c], whB[1][c], ra);
      na = MFMA(hA[c], whB[2][c], na);
    }
    if (w < 4) {
      const h8 xA2 = *(const h8*)(xB + XOFF(t + 2));
      f32x4 ea = {be, be, be, be};
      ea = MFMA(xA2, wencB, ea);
#pragma unroll
      for (int r = 0; r < 4; ++r) {
        const int brow = rb + r;
        *(_Float16*)(eB + q * 2048 + brow * 128 +
                     (((16 * w + col) * 2) ^ ((brow & 7) << 4))) = (_Float16)tanh_f(ea[r]);
      }
    } else if (w == 4) {
      f32x4 ga = {bgv, bgv, bgv, bgv};
#pragma unroll
      for (int c = 0; c < 4; ++c) ga = MFMA(hA[c], wgB[c], ga);
      float mx[4], ev[4], sv[4];
#pragma unroll
      for (int r = 0; r < 4; ++r) mx[r] = ga[r];
#pragma unroll
      for (int mk = 1; mk <= 4; mk <<= 1)
#pragma unroll
        for (int r = 0; r < 4; ++r) mx[r] = fmaxf(mx[r], __shfl_xor(mx[r], mk, 64));
#pragma unroll
      for (int r = 0; r < 4; ++r) { ev[r] = __expf(ga[r] - mx[r]); sv[r] = ev[r]; }
#pragma unroll
      for (int mk = 1; mk <= 4; mk <<= 1)
#pragma unroll
        for (int r = 0; r < 4; ++r) sv[r] += __shfl_xor(sv[r], mk, 64);
      if (col < 8) {
#pragma unroll
        for (int r = 0; r < 4; ++r) g_sh[col][rb + r] = ev[r] * rcpf(sv[r]);
      }
    }
    __syncthreads();
    // ============ Phase B ============
    // 1. kst(t-1) A-fragment in-register (redundant per wave)
    float gv[8];
#pragma unroll
    for (int m = 0; m < 8; ++m) gv[m] = g_sh[m][bA];
    h8 nsv[8];
#pragma unroll
    for (int m = 0; m < 8; ++m) nsv[m] = *(const h8*)(nsB + NSOFF(qp, m));
    float kf[8];
#pragma unroll
    for (int e = 0; e < 8; ++e) {
      float acc = gv[0] * (float)nsv[0][e];
#pragma unroll
      for (int m = 1; m < 8; ++m) acc += gv[m] * (float)nsv[m][e];
      kf[e] = acc;
    }
    h8 kstA;
#pragma unroll
    for (int e = 0; e < 8; ++e) kstA[e] = (_Float16)kf[e];
    // 2. err(t-1) broadcast via in-wave bpermute (source lanes 48..63)
    float myerr = (t == 0) ? 0.f : (kf[7] - y_sh[bA][t & 127]);
    const int esrc = __float_as_int(myerr);
    float errv[4];
#pragma unroll
    for (int r = 0; r < 4; ++r)
      errv[r] = __int_as_float(
          __builtin_amdgcn_ds_bpermute((48 + rb + r) * 4, esrc));
    if (w == 0 && kg == 3 && t > 0)
      out[(size_t)(bg * BPB + bA) * NT + t - 1] = kf[7];
    // 3. ns(t) MFMA + tanh -> ns_shm[q]
    {
      const f32x4 nsa0 = MFMA(kstA, wrecB[0], xdaC0);
      const f32x4 nsa1 = MFMA(kstA, wrecB[1], xdaC1);
#pragma unroll
      for (int r = 0; r < 4; ++r) {
        const int brow = rb + r;
        char* nb = nsB + q * 8192 + brow * 512;
        *(_Float16*)(nb + ((w * 64 + (0 * 16 + col) * 2) ^ ((brow & 7) << 4))) =
            (_Float16)tanh_f(nsa0[r]);
        *(_Float16*)(nb + ((w * 64 + (1 * 16 + col) * 2) ^ ((brow & 7) << 4))) =
            (_Float16)tanh_f(nsa1[r]);
      }
    }
    // 4. xpre(t+1), xd(t+1) into next-regs
    f32x4 xpaN0, xpaN1, xpaN2, xdaN0, xdaN1;
    {
      const h8 encA0 = *(const h8*)(eB + EOFF(qp, 0));
      const h8 encA1 = *(const h8*)(eB + EOFF(qp, 1));
      f32x4 a0 = {bx3[0], bx3[0], bx3[0], bx3[0]};
      f32x4 a1 = {bx3[1], bx3[1], bx3[1], bx3[1]};
      f32x4 a2 = {bx3[2], bx3[2], bx3[2], bx3[2]};
      a0 = MFMA(encA0, wxB[0][0], a0); a0 = MFMA(encA1, wxB[0][1], a0);
      a1 = MFMA(encA0, wxB[1][0], a1); a1 = MFMA(encA1, wxB[1][1], a1);
      a2 = MFMA(encA0, wxB[2][0], a2); a2 = MFMA(encA1, wxB[2][1], a2);
      xpaN0 = a0; xpaN1 = a1; xpaN2 = a2;
      const h8 xA1 = *(const h8*)(xB + XOFF(t + 1));
      f32x4 d0 = {bs2[0], bs2[0], bs2[0], bs2[0]};
      f32x4 d1 = {bs2[1], bs2[1], bs2[1], bs2[1]};
      xdaN0 = MFMA(xA1, winB[0], d0);
      xdaN1 = MFMA(xA1, winB[1], d1);
    }
    // 5. GRU pointwise -> h_shm[q]
#pragma unroll
    for (int r = 0; r < 4; ++r) {
      const float z = sigmoid_f(za[r] + xpaC0[r] + errv[r] * wxe3[0]);
      const float rr = sigmoid_f(ra[r] + xpaC1[r] + errv[r] * wxe3[1]);
      const float n = tanh_f(xpaC2[r] + errv[r] * wxe3[2] + rr * na[r]);
      const float hnew = (1.f - z) * n + z * h_prev[r];
      h_prev[r] = hnew;
      const int brow = rb + r;
      *(_Float16*)(hB + q * 4096 + brow * 256 + ((jc * 2) ^ ((brow & 7) << 4))) =
          (_Float16)hnew;
    }
    xpaC0 = xpaN0; xpaC1 = xpaN1; xpaC2 = xpaN2;
    xdaC0 = xdaN0; xdaC1 = xdaN1;
    // 6. slab reloads
    if ((t & 31) == 29) LOAD_X_SLAB(((t >> 5) + 1) & 1, (t & ~31) + 32)
    if ((t & 127) == 127 && t + 1 < NT) LOAD_Y_SLAB(t + 1)
    __syncthreads();
  }

  // ---- epilogue: gate(NT-1) -> kst(NT-1)[31] -> out[NT-1] ----
  if (w == 4) {
    h8 hA[4];
#pragma unroll
    for (int c = 0; c < 4; ++c) hA[c] = *(const h8*)(hB + HOFF(1, c));
    f32x4 ga = {bgv, bgv, bgv, bgv};
#pragma unroll
    for (int c = 0; c < 4; ++c) ga = MFMA(hA[c], wgB[c], ga);
    float mx[4], ev[4], sv[4];
#pragma unroll
    for (int r = 0; r < 4; ++r) mx[r] = ga[r];
#pragma unroll
    for (int mk = 1; mk <= 4; mk <<= 1)
#pragma unroll
      for (int r = 0; r < 4; ++r) mx[r] = fmaxf(mx[r], __shfl_xor(mx[r], mk, 64));
#pragma unroll
    for (int r = 0; r < 4; ++r) { ev[r] = __expf(ga[r] - mx[r]); sv[r] = ev[r]; }
#pragma unroll
    for (int mk = 1; mk <= 4; mk <<= 1)
#pragma unroll
      for (int r = 0; r < 4; ++r) sv[r] += __shfl_xor(sv[r], mk, 64);
    if (col < 8) {
#pragma unroll
      for (int r = 0; r < 4; ++r) g_sh[col][rb + r] = ev[r] * rcpf(sv[r]);
    }
  }
  __syncthreads();
  if (w == 0 && kg == 3) {
    float kv = 0.f;
#pragma unroll
    for (int m = 0; m < 8; ++m) {
      const _Float16 nh =
          *(const _Float16*)(nsB + 8192 + bA * 512 + ((m * 64 + 62) ^ ((bA & 7) << 4)));
      kv += g_sh[m][bA] * (float)nh;
    }
    out[(size_t)(bg * BPB + bA) * NT + NT - 1] = kv;
  }
}

extern "C" void kernel_launch(void* const* d_in, const int* in_sizes, int n_in,
                              void* d_out, int out_size, void* d_ws, size_t ws_size,
                              hipStream_t stream) {
  const float* x = (const float*)d_in[0];
  const float* y = (const float*)d_in[1];
  const float* W_enc = (const float*)d_in[2];
  const float* b_enc = (const float*)d_in[3];
  const float* W_in = (const float*)d_in[4];
  const float* W_rec = (const float*)d_in[5];
  const float* b_s = (const float*)d_in[6];
  const float* W_x = (const float*)d_in[7];
  const float* W_h = (const float*)d_in[8];
  const float* b_x = (const float*)d_in[9];
  const float* b_h = (const float*)d_in[10];
  const float* W_gate = (const float*)d_in[11];
  const float* b_gate = (const float*)d_in[12];
  float* out = (float*)d_out;

  rnn_mfma2<<<dim3(NB / BPB), dim3(512), 0, stream>>>(
      x, y, W_enc, b_enc, W_in, W_rec, b_s, W_x, W_h, b_x, b_h, W_gate, b_gate,
      out);
}